// Round 1
// baseline (1073.436 us; speedup 1.0000x reference)
//
#include <hip/hip_runtime.h>
#include <math.h>

#define Bb   4
#define Ss   16
#define Nn   2048
#define Ff   32
#define Ee   16384
#define EFf  8
#define Hh   64
#define HB2  32
#define E2c  (Ee + Nn)          // 18432
#define RTOT (Bb*Ss*Nn)         // 131072
#define Mm   (Ss*Nn)            // 32768

// ---------------------------------------------------------------------------
// Self-loop attr accumulation: cnt[d] += 1, loop[d][j] += edge_attr[e][j]
// ---------------------------------------------------------------------------
__global__ __launch_bounds__(256) void k_loop_accum(
    const int* __restrict__ ei, const float* __restrict__ ea,
    float* __restrict__ cntF, float* __restrict__ loopA) {
  int idx = blockIdx.x * 256 + threadIdx.x;
  if (idx >= Ee * EFf) return;
  int e = idx >> 3, j = idx & 7;
  int d = ei[Ee + e];               // dst row of edge_index
  atomicAdd(&loopA[d * EFf + j], ea[idx]);
  if (j == 0) atomicAdd(&cntF[d], 1.0f);
}

__global__ __launch_bounds__(256) void k_loop_div(
    float* __restrict__ loopA, const float* __restrict__ cntF) {
  int idx = blockIdx.x * 256 + threadIdx.x;
  if (idx >= Nn * EFf) return;
  loopA[idx] /= fmaxf(cntF[idx >> 3], 1.0f);
}

// ---------------------------------------------------------------------------
// Exclusive scan of per-dst counts (+1 self loop each) -> offs[0..2048]
// Single block, 256 threads, 8 elements each.
// ---------------------------------------------------------------------------
__global__ __launch_bounds__(256) void k_scan(
    const float* __restrict__ cntF, int* __restrict__ offs) {
  __shared__ int partial[256];
  int tid = threadIdx.x;
  int base = tid * 8;
  int vals[8];
  int s = 0;
  for (int i = 0; i < 8; ++i) {
    int c = (int)cntF[base + i] + 1;   // +1 self loop
    vals[i] = c;
    s += c;
  }
  partial[tid] = s;
  __syncthreads();
  for (int off = 1; off < 256; off <<= 1) {
    int v = partial[tid];
    int add = (tid >= off) ? partial[tid - off] : 0;
    __syncthreads();
    partial[tid] = v + add;
    __syncthreads();
  }
  int run = (tid == 0) ? 0 : partial[tid - 1];
  for (int i = 0; i < 8; ++i) {
    offs[base + i] = run;
    run += vals[i];
  }
  if (tid == 255) offs[Nn] = run;   // == E2c
}

// ---------------------------------------------------------------------------
// Scatter edges into CSR-by-dst. Order within a bucket irrelevant (softmax).
// ---------------------------------------------------------------------------
__global__ __launch_bounds__(256) void k_scatter(
    const int* __restrict__ ei, const int* __restrict__ offs,
    int* __restrict__ fillI, int* __restrict__ eidA, int* __restrict__ srcA) {
  int e = blockIdx.x * 256 + threadIdx.x;
  if (e >= E2c) return;
  int d = (e < Ee) ? ei[Ee + e] : (e - Ee);
  int s = (e < Ee) ? ei[e]      : (e - Ee);
  int pos = offs[d] + atomicAdd(&fillI[d], 1);
  eidA[pos] = e;
  srcA[pos] = s;
}

// ---------------------------------------------------------------------------
// ep = ea_f @ We[l]   (ea_f row = edge_attr[e] or loop_attr[e-E])
// One thread per (edge, out-col).
// ---------------------------------------------------------------------------
__global__ __launch_bounds__(256) void k_ep(
    const float* __restrict__ ea, const float* __restrict__ loopA,
    const float* __restrict__ We, float* __restrict__ EP) {
  __shared__ float wlds[EFf * Hh];
  int tid = threadIdx.x;
  if (tid < EFf * Hh) wlds[tid] = We[tid];
  if (tid + 256 < EFf * Hh) wlds[tid + 256] = We[tid + 256];
  __syncthreads();
  int idx = blockIdx.x * 256 + tid;
  if (idx >= E2c * Hh) return;
  int e = idx >> 6, j = idx & 63;
  const float* a = (e < Ee) ? (ea + (size_t)e * EFf) : (loopA + (size_t)(e - Ee) * EFf);
  float acc = 0.f;
#pragma unroll
  for (int k = 0; k < EFf; ++k) acc += a[k] * wlds[k * Hh + j];
  EP[idx] = acc;
}

// ---------------------------------------------------------------------------
// Generic row-parallel GEMM: Out[r][c0+j] = bias[c0+j] + sum_k X[r][k]*W(k,j)
// W(k,j) = wT ? W[j*K+k] : W[k*Nout+j].  blockIdx.y picks a 64-col slice.
// ---------------------------------------------------------------------------
template <int K>
__global__ __launch_bounds__(256) void k_gemm(
    const float* __restrict__ Xin, const float* __restrict__ W,
    const float* __restrict__ bias, float* __restrict__ Out,
    int rows, int Nout, int wT) {
  __shared__ float wlds[K * 64];
  __shared__ float blds[64];
  int tid = threadIdx.x;
  int c0 = blockIdx.y * 64;
  for (int idx = tid; idx < K * 64; idx += 256) {
    int k = idx >> 6, jj = idx & 63;
    wlds[idx] = wT ? W[(size_t)(c0 + jj) * K + k] : W[(size_t)k * Nout + c0 + jj];
  }
  if (tid < 64) blds[tid] = bias[c0 + tid];
  __syncthreads();
  int r = blockIdx.x * 256 + tid;
  if (r >= rows) return;
  float x[K];
  const float4* xp = (const float4*)(Xin + (size_t)r * K);
#pragma unroll
  for (int q = 0; q < K / 4; ++q) {
    float4 v = xp[q];
    x[4 * q] = v.x; x[4 * q + 1] = v.y; x[4 * q + 2] = v.z; x[4 * q + 3] = v.w;
  }
  float* outp = Out + (size_t)r * Nout + c0;
  for (int jc = 0; jc < 64; jc += 16) {
    float acc[16];
#pragma unroll
    for (int j = 0; j < 16; ++j) acc[j] = blds[jc + j];
#pragma unroll
    for (int k = 0; k < K; ++k) {
      const float4* wp = (const float4*)(wlds + (k << 6) + jc);
      float4 w0 = wp[0], w1 = wp[1], w2 = wp[2], w3 = wp[3];
      float xv = x[k];
      acc[0]  += xv * w0.x; acc[1]  += xv * w0.y; acc[2]  += xv * w0.z; acc[3]  += xv * w0.w;
      acc[4]  += xv * w1.x; acc[5]  += xv * w1.y; acc[6]  += xv * w1.z; acc[7]  += xv * w1.w;
      acc[8]  += xv * w2.x; acc[9]  += xv * w2.y; acc[10] += xv * w2.z; acc[11] += xv * w2.w;
      acc[12] += xv * w3.x; acc[13] += xv * w3.y; acc[14] += xv * w3.z; acc[15] += xv * w3.w;
    }
    float4* op = (float4*)(outp + jc);
    op[0] = make_float4(acc[0],  acc[1],  acc[2],  acc[3]);
    op[1] = make_float4(acc[4],  acc[5],  acc[6],  acc[7]);
    op[2] = make_float4(acc[8],  acc[9],  acc[10], acc[11]);
    op[3] = make_float4(acc[12], acc[13], acc[14], acc[15]);
  }
}

// ---------------------------------------------------------------------------
// GATv2 per-(graph,dst) online-softmax aggregation.
// One wave per (g,d); lane = H component. Writes hg over XR in place
// (each wave is the sole reader/writer of its own XR row).
// ---------------------------------------------------------------------------
__global__ __launch_bounds__(256) void k_gat(
    const float* __restrict__ XL, float* __restrict__ XR_HG,
    const float* __restrict__ EP, const int* __restrict__ offs,
    const int* __restrict__ eidA, const int* __restrict__ srcA,
    const float* __restrict__ att, const float* __restrict__ gbl) {
  int gw = (blockIdx.x * 256 + threadIdx.x) >> 6;
  if (gw >= (Bb * Ss) * Nn) return;
  int lane = threadIdx.x & 63;
  int g = gw >> 11;          // / Nn
  int d = gw & (Nn - 1);
  float attv = att[lane];
  size_t rowbase = ((size_t)(g * Nn + d)) * Hh;
  float xr = XR_HG[rowbase + lane];
  int p0 = offs[d], p1 = offs[d + 1];
  float Mrun = -INFINITY, Ssum = 0.f, acc = 0.f;
  for (int p = p0; p < p1; ++p) {
    int e = eidA[p];
    int s = srcA[p];
    float xl = XL[((size_t)(g * Nn + s)) * Hh + lane];
    float m = xl + xr + EP[(size_t)e * Hh + lane];
    m = (m > 0.f) ? m : 0.2f * m;              // leaky_relu 0.2
    float v = m * attv;
#pragma unroll
    for (int w = 1; w < 64; w <<= 1) v += __shfl_xor(v, w, 64);
    float newM = fmaxf(Mrun, v);
    float sc = expf(Mrun - newM);              // exp(-inf)=0 first iter
    float we = expf(v - newM);
    Ssum = Ssum * sc + we;
    acc  = acc  * sc + we * xl;
    Mrun = newM;
  }
  XR_HG[rowbase + lane] = acc / Ssum + gbl[lane];
}

// ---------------------------------------------------------------------------
// GRU gate combine. GH==null -> t=0 (gh = bhh, hprev = 0).
// ---------------------------------------------------------------------------
__global__ __launch_bounds__(256) void k_gru_elt(
    const float* __restrict__ GI, const float* __restrict__ GH,
    const float* __restrict__ bhh, const float* __restrict__ Hprev,
    float* __restrict__ Hout) {
  int idx = blockIdx.x * 256 + threadIdx.x;
  if (idx >= Mm * Hh) return;
  int r = idx >> 6, k = idx & 63;
  size_t rb = (size_t)r * 192;
  float ir = GI[rb + k], iz = GI[rb + 64 + k], in_ = GI[rb + 128 + k];
  float hr, hz, hn;
  if (GH) { hr = GH[rb + k]; hz = GH[rb + 64 + k]; hn = GH[rb + 128 + k]; }
  else    { hr = bhh[k];     hz = bhh[64 + k];     hn = bhh[128 + k]; }
  float hp = Hprev ? Hprev[idx] : 0.f;
  float rg = 1.f / (1.f + expf(-(ir + hr)));
  float zg = 1.f / (1.f + expf(-(iz + hz)));
  float ng = tanhf(in_ + rg * hn);
  Hout[idx] = (1.f - zg) * ng + zg * hp;
}

// ---------------------------------------------------------------------------
// Output heads: order/demand = relu(xl@W1+b1)@W2+b2, xl = X[:, -1]
// ---------------------------------------------------------------------------
__global__ __launch_bounds__(256) void k_heads(
    const float* __restrict__ Xb,
    const float* __restrict__ oW1, const float* __restrict__ ob1,
    const float* __restrict__ oW2, const float* __restrict__ ob2,
    const float* __restrict__ dW1, const float* __restrict__ db1,
    const float* __restrict__ dW2, const float* __restrict__ db2,
    float* __restrict__ out) {
  __shared__ float w1o[Hh * HB2], w1d[Hh * HB2];
  __shared__ float w2o[HB2], w2d[HB2], b1o[HB2], b1d[HB2];
  int tid = threadIdx.x;
  for (int idx = tid; idx < Hh * HB2; idx += 256) { w1o[idx] = oW1[idx]; w1d[idx] = dW1[idx]; }
  if (tid < HB2) { w2o[tid] = oW2[tid]; w2d[tid] = dW2[tid]; b1o[tid] = ob1[tid]; b1d[tid] = db1[tid]; }
  __syncthreads();
  int r = blockIdx.x * 256 + tid;
  if (r >= Bb * Nn) return;
  int b = r >> 11, n = r & (Nn - 1);
  const float* xrow = Xb + (((size_t)b * Ss + (Ss - 1)) * Nn + n) * Hh;
  float x[Hh];
  const float4* xp = (const float4*)xrow;
#pragma unroll
  for (int q = 0; q < Hh / 4; ++q) {
    float4 v = xp[q];
    x[4 * q] = v.x; x[4 * q + 1] = v.y; x[4 * q + 2] = v.z; x[4 * q + 3] = v.w;
  }
  float acco = ob2[0], accd = db2[0];
  for (int j = 0; j < HB2; ++j) {
    float ho = b1o[j], hd = b1d[j];
#pragma unroll
    for (int k = 0; k < Hh; ++k) {
      ho += x[k] * w1o[k * HB2 + j];
      hd += x[k] * w1d[k * HB2 + j];
    }
    acco += fmaxf(ho, 0.f) * w2o[j];
    accd += fmaxf(hd, 0.f) * w2d[j];
  }
  out[r] = acco;
  out[Bb * Nn + r] = accd;
}

// ---------------------------------------------------------------------------
extern "C" void kernel_launch(void* const* d_in, const int* in_sizes, int n_in,
                              void* d_out, int out_size, void* d_ws, size_t ws_size,
                              hipStream_t stream) {
  const float* x   = (const float*)d_in[0];
  const int*   ei  = (const int*)d_in[1];
  const float* ea  = (const float*)d_in[2];
  const float* Wp  = (const float*)d_in[3];
  const float* bp  = (const float*)d_in[4];
  const float* Wl  = (const float*)d_in[5];
  const float* bl  = (const float*)d_in[6];
  const float* Wr  = (const float*)d_in[7];
  const float* br  = (const float*)d_in[8];
  const float* We  = (const float*)d_in[9];
  const float* att = (const float*)d_in[10];
  const float* gb  = (const float*)d_in[11];
  const float* Wih = (const float*)d_in[12];
  const float* Whh = (const float*)d_in[13];
  const float* bih = (const float*)d_in[14];
  const float* bhh = (const float*)d_in[15];
  const float* oW1 = (const float*)d_in[16];
  const float* ob1 = (const float*)d_in[17];
  const float* oW2 = (const float*)d_in[18];
  const float* ob2 = (const float*)d_in[19];
  const float* dW1 = (const float*)d_in[20];
  const float* db1 = (const float*)d_in[21];
  const float* dW2 = (const float*)d_in[22];
  const float* db2 = (const float*)d_in[23];
  float* out = (float*)d_out;

  // workspace layout (floats)
  float* f    = (float*)d_ws;
  float* Xb   = f;                          // 131072*64
  float* XLb  = Xb  + (size_t)RTOT * Hh;    // 131072*64 (reused as GH)
  float* XRb  = XLb + (size_t)RTOT * Hh;    // 131072*64 (reused as HG)
  float* GIb  = XRb + (size_t)RTOT * Hh;    // 32768*192
  float* EPb  = GIb + (size_t)Mm * 192;     // 18432*64
  float* cntF = EPb + (size_t)E2c * Hh;     // 2048
  float* loopA = cntF + Nn;                 // 2048*8
  int*   fillI = (int*)(loopA + Nn * EFf);  // 2048
  int*   offs  = fillI + Nn;                // 2049 (+pad)
  int*   eidA  = offs + 2052;               // 18432
  int*   srcA  = eidA + E2c;                // 18432
  float* GHb   = XLb;                       // gh buffer aliases XL (free after k_gat)

  // zero cnt / loop_attr / fill (contiguous)
  hipMemsetAsync(cntF, 0, (size_t)(Nn + Nn * EFf + Nn) * 4, stream);

  // self-loop mean attrs + CSR build (edge_index independent of layer/graph)
  k_loop_accum<<<dim3((Ee * EFf + 255) / 256), 256, 0, stream>>>(ei, ea, cntF, loopA);
  k_loop_div<<<dim3((Nn * EFf + 255) / 256), 256, 0, stream>>>(loopA, cntF);
  k_scan<<<1, 256, 0, stream>>>(cntF, offs);
  k_scatter<<<dim3((E2c + 255) / 256), 256, 0, stream>>>(ei, offs, fillI, eidA, srcA);

  // X = x @ Wp + bp
  k_gemm<Ff><<<dim3(RTOT / 256, 1), 256, 0, stream>>>(x, Wp, bp, Xb, RTOT, Hh, 0);

  for (int l = 0; l < 2; ++l) {
    // ep = ea_f @ We[l]
    k_ep<<<dim3((E2c * Hh + 255) / 256), 256, 0, stream>>>(
        ea, loopA, We + (size_t)l * EFf * Hh, EPb);
    // XL / XR
    k_gemm<Hh><<<dim3(RTOT / 256, 1), 256, 0, stream>>>(
        Xb, Wl + (size_t)l * Hh * Hh, bl + (size_t)l * Hh, XLb, RTOT, Hh, 0);
    k_gemm<Hh><<<dim3(RTOT / 256, 1), 256, 0, stream>>>(
        Xb, Wr + (size_t)l * Hh * Hh, br + (size_t)l * Hh, XRb, RTOT, Hh, 0);
    // GAT aggregation -> hg (in place over XR)
    k_gat<<<dim3(RTOT * Hh / 256), 256, 0, stream>>>(
        XLb, XRb, EPb, offs, eidA, srcA, att + (size_t)l * Hh, gb + (size_t)l * Hh);
    // GRU over T = B = 4 steps; hg slices are the inputs, h_t written into Xb
    for (int t = 0; t < Bb; ++t) {
      const float* hg_t = XRb + (size_t)t * Mm * Hh;
      float* h_out = Xb + (size_t)t * Mm * Hh;
      const float* h_prev = (t > 0) ? (Xb + (size_t)(t - 1) * Mm * Hh) : nullptr;
      k_gemm<Hh><<<dim3(Mm / 256, 3), 256, 0, stream>>>(
          hg_t, Wih + (size_t)l * 192 * Hh, bih + (size_t)l * 192, GIb, Mm, 192, 1);
      if (t > 0) {
        k_gemm<Hh><<<dim3(Mm / 256, 3), 256, 0, stream>>>(
            h_prev, Whh + (size_t)l * 192 * Hh, bhh + (size_t)l * 192, GHb, Mm, 192, 1);
      }
      k_gru_elt<<<dim3(Mm * Hh / 256), 256, 0, stream>>>(
          GIb, (t > 0) ? GHb : nullptr, bhh + (size_t)l * 192, h_prev, h_out);
    }
  }

  // heads
  k_heads<<<dim3((Bb * Nn + 255) / 256), 256, 0, stream>>>(
      Xb, oW1, ob1, oW2, ob2, dW1, db1, dW2, db2, out);
}

// Round 2
// 829.900 us; speedup vs baseline: 1.2935x; 1.2935x over previous
//
#include <hip/hip_runtime.h>
#include <math.h>

#define Bb   4
#define Ss   16
#define Nn   2048
#define Ff   32
#define Ee   16384
#define EFf  8
#define Hh   64
#define HB2  32
#define E2c  (Ee + Nn)          // 18432
#define RTOT (Bb*Ss*Nn)         // 131072
#define Mm   (Ss*Nn)            // 32768

__device__ __forceinline__ float sigf(float x) { return 1.f / (1.f + __expf(-x)); }
__device__ __forceinline__ float tanhfast(float x) { return 2.f / (1.f + __expf(-2.f * x)) - 1.f; }

// ---------------------------------------------------------------------------
// Self-loop attr accumulation
// ---------------------------------------------------------------------------
__global__ __launch_bounds__(256) void k_loop_accum(
    const int* __restrict__ ei, const float* __restrict__ ea,
    float* __restrict__ cntF, float* __restrict__ loopA) {
  int idx = blockIdx.x * 256 + threadIdx.x;
  if (idx >= Ee * EFf) return;
  int e = idx >> 3, j = idx & 7;
  int d = ei[Ee + e];
  atomicAdd(&loopA[d * EFf + j], ea[idx]);
  if (j == 0) atomicAdd(&cntF[d], 1.0f);
}

__global__ __launch_bounds__(256) void k_loop_div(
    float* __restrict__ loopA, const float* __restrict__ cntF) {
  int idx = blockIdx.x * 256 + threadIdx.x;
  if (idx >= Nn * EFf) return;
  loopA[idx] /= fmaxf(cntF[idx >> 3], 1.0f);
}

// ---------------------------------------------------------------------------
// Exclusive scan of per-dst counts (+1 self loop) -> offs[0..2048]
// ---------------------------------------------------------------------------
__global__ __launch_bounds__(256) void k_scan(
    const float* __restrict__ cntF, int* __restrict__ offs) {
  __shared__ int partial[256];
  int tid = threadIdx.x;
  int base = tid * 8;
  int vals[8];
  int s = 0;
  for (int i = 0; i < 8; ++i) {
    int c = (int)cntF[base + i] + 1;
    vals[i] = c;
    s += c;
  }
  partial[tid] = s;
  __syncthreads();
  for (int off = 1; off < 256; off <<= 1) {
    int v = partial[tid];
    int add = (tid >= off) ? partial[tid - off] : 0;
    __syncthreads();
    partial[tid] = v + add;
    __syncthreads();
  }
  int run = (tid == 0) ? 0 : partial[tid - 1];
  for (int i = 0; i < 8; ++i) {
    offs[base + i] = run;
    run += vals[i];
  }
  if (tid == 255) offs[Nn] = run;
}

__global__ __launch_bounds__(256) void k_scatter(
    const int* __restrict__ ei, const int* __restrict__ offs,
    int* __restrict__ fillI, int* __restrict__ eidA, int* __restrict__ srcA) {
  int e = blockIdx.x * 256 + threadIdx.x;
  if (e >= E2c) return;
  int d = (e < Ee) ? ei[Ee + e] : (e - Ee);
  int s = (e < Ee) ? ei[e]      : (e - Ee);
  int pos = offs[d] + atomicAdd(&fillI[d], 1);
  eidA[pos] = e;
  srcA[pos] = s;
}

// ---------------------------------------------------------------------------
// ep = ea_f @ We[l]
// ---------------------------------------------------------------------------
__global__ __launch_bounds__(256) void k_ep(
    const float* __restrict__ ea, const float* __restrict__ loopA,
    const float* __restrict__ We, float* __restrict__ EP) {
  __shared__ float wlds[EFf * Hh];
  int tid = threadIdx.x;
  if (tid < EFf * Hh) wlds[tid] = We[tid];
  if (tid + 256 < EFf * Hh) wlds[tid + 256] = We[tid + 256];
  __syncthreads();
  int idx = blockIdx.x * 256 + tid;
  if (idx >= E2c * Hh) return;
  int e = idx >> 6, j = idx & 63;
  const float* a = (e < Ee) ? (ea + (size_t)e * EFf) : (loopA + (size_t)(e - Ee) * EFf);
  float acc = 0.f;
#pragma unroll
  for (int k = 0; k < EFf; ++k) acc += a[k] * wlds[k * Hh + j];
  EP[idx] = acc;
}

// ---------------------------------------------------------------------------
// Generic row-parallel GEMM (used for input projection only now)
// ---------------------------------------------------------------------------
template <int K>
__global__ __launch_bounds__(256) void k_gemm(
    const float* __restrict__ Xin, const float* __restrict__ W,
    const float* __restrict__ bias, float* __restrict__ Out,
    int rows, int Nout, int wT) {
  __shared__ float wlds[K * 64];
  __shared__ float blds[64];
  int tid = threadIdx.x;
  int c0 = blockIdx.y * 64;
  for (int idx = tid; idx < K * 64; idx += 256) {
    int k = idx >> 6, jj = idx & 63;
    wlds[idx] = wT ? W[(size_t)(c0 + jj) * K + k] : W[(size_t)k * Nout + c0 + jj];
  }
  if (tid < 64) blds[tid] = bias[c0 + tid];
  __syncthreads();
  int r = blockIdx.x * 256 + tid;
  if (r >= rows) return;
  float x[K];
  const float4* xp = (const float4*)(Xin + (size_t)r * K);
#pragma unroll
  for (int q = 0; q < K / 4; ++q) {
    float4 v = xp[q];
    x[4 * q] = v.x; x[4 * q + 1] = v.y; x[4 * q + 2] = v.z; x[4 * q + 3] = v.w;
  }
  float* outp = Out + (size_t)r * Nout + c0;
  for (int jc = 0; jc < 64; jc += 16) {
    float acc[16];
#pragma unroll
    for (int j = 0; j < 16; ++j) acc[j] = blds[jc + j];
#pragma unroll
    for (int k = 0; k < K; ++k) {
      const float4* wp = (const float4*)(wlds + (k << 6) + jc);
      float4 w0 = wp[0], w1 = wp[1], w2 = wp[2], w3 = wp[3];
      float xv = x[k];
      acc[0]  += xv * w0.x; acc[1]  += xv * w0.y; acc[2]  += xv * w0.z; acc[3]  += xv * w0.w;
      acc[4]  += xv * w1.x; acc[5]  += xv * w1.y; acc[6]  += xv * w1.z; acc[7]  += xv * w1.w;
      acc[8]  += xv * w2.x; acc[9]  += xv * w2.y; acc[10] += xv * w2.z; acc[11] += xv * w2.w;
      acc[12] += xv * w3.x; acc[13] += xv * w3.y; acc[14] += xv * w3.z; acc[15] += xv * w3.w;
    }
    float4* op = (float4*)(outp + jc);
    op[0] = make_float4(acc[0],  acc[1],  acc[2],  acc[3]);
    op[1] = make_float4(acc[4],  acc[5],  acc[6],  acc[7]);
    op[2] = make_float4(acc[8],  acc[9],  acc[10], acc[11]);
    op[3] = make_float4(acc[12], acc[13], acc[14], acc[15]);
  }
}

// ---------------------------------------------------------------------------
// Fused XL/XR: reads X once, writes both projections. 16-col slice per block.y
// ---------------------------------------------------------------------------
__global__ __launch_bounds__(256) void k_xlr(
    const float* __restrict__ X,
    const float* __restrict__ Wl_, const float* __restrict__ bl_,
    const float* __restrict__ Wr_, const float* __restrict__ br_,
    float* __restrict__ XL, float* __restrict__ XR) {
  __shared__ float wlds[2 * 64 * 16];
  int tid = threadIdx.x;
  int j0 = blockIdx.y * 16;
  for (int idx = tid; idx < 2 * 64 * 16; idx += 256) {
    int m = idx >> 10;
    int k = (idx >> 4) & 63;
    int jj = idx & 15;
    const float* src = m ? Wr_ : Wl_;
    wlds[idx] = src[(size_t)k * 64 + j0 + jj];  // wlds[(m*64+k)*16+jj]
  }
  __syncthreads();
  int r = blockIdx.x * 256 + tid;
  float4 accL[4], accR[4];
#pragma unroll
  for (int q = 0; q < 4; ++q) {
    accL[q] = *(const float4*)(bl_ + j0 + 4 * q);
    accR[q] = *(const float4*)(br_ + j0 + 4 * q);
  }
  const float* xr = X + ((size_t)r << 6);
  for (int kc = 0; kc < 64; kc += 4) {
    float4 xv = *(const float4*)(xr + kc);
    float xa[4] = {xv.x, xv.y, xv.z, xv.w};
#pragma unroll
    for (int q = 0; q < 4; ++q) {
      int k = kc + q;
      const float4* wL = (const float4*)(wlds + (k << 4));
      const float4* wR = (const float4*)(wlds + ((64 + k) << 4));
      float s = xa[q];
#pragma unroll
      for (int q4 = 0; q4 < 4; ++q4) {
        float4 wl4 = wL[q4], wr4 = wR[q4];
        accL[q4].x = fmaf(wl4.x, s, accL[q4].x);
        accL[q4].y = fmaf(wl4.y, s, accL[q4].y);
        accL[q4].z = fmaf(wl4.z, s, accL[q4].z);
        accL[q4].w = fmaf(wl4.w, s, accL[q4].w);
        accR[q4].x = fmaf(wr4.x, s, accR[q4].x);
        accR[q4].y = fmaf(wr4.y, s, accR[q4].y);
        accR[q4].z = fmaf(wr4.z, s, accR[q4].z);
        accR[q4].w = fmaf(wr4.w, s, accR[q4].w);
      }
    }
  }
  size_t ob = ((size_t)r << 6) + j0;
#pragma unroll
  for (int q = 0; q < 4; ++q) {
    *(float4*)(XL + ob + 4 * q) = accL[q];
    *(float4*)(XR + ob + 4 * q) = accR[q];
  }
}

// ---------------------------------------------------------------------------
// GATv2: wave per (g,d), lane = h. Preloaded edge list, no-max softmax, __expf.
// ---------------------------------------------------------------------------
__global__ __launch_bounds__(256) void k_gat(
    const float* __restrict__ XL, float* __restrict__ XR_HG,
    const float* __restrict__ EP, const int* __restrict__ offs,
    const int* __restrict__ eidA, const int* __restrict__ srcA,
    const float* __restrict__ att, const float* __restrict__ gbl) {
  int gw = (blockIdx.x * 256 + threadIdx.x) >> 6;
  if (gw >= (Bb * Ss) * Nn) return;
  int lane = threadIdx.x & 63;
  int g = gw >> 11;
  int d = gw & (Nn - 1);
  float attv = att[lane];
  size_t rowbase = ((size_t)(g * Nn + d)) * Hh;
  float xr = XR_HG[rowbase + lane];
  int p0 = offs[d], p1 = offs[d + 1];
  int nE = p1 - p0;
  int eidv = 0, srcv = 0;
  if (lane < nE) { eidv = eidA[p0 + lane]; srcv = srcA[p0 + lane]; }
  const float* XLg = XL + ((size_t)g * Nn) * Hh;
  float Ssum = 0.f, acc = 0.f;
  for (int p = 0; p < nE; ++p) {
    int e, s;
    if (p < 64) {
      e = __shfl(eidv, p, 64);
      s = __shfl(srcv, p, 64);
    } else {
      e = eidA[p0 + p];
      s = srcA[p0 + p];
    }
    float xl = XLg[((size_t)s << 6) + lane];
    float m = xl + xr + EP[((size_t)e << 6) + lane];
    m = fmaxf(m, 0.2f * m);                 // leaky_relu(0.2)
    float v = m * attv;
#pragma unroll
    for (int w = 1; w < 64; w <<= 1) v += __shfl_xor(v, w, 64);
    float we = __expf(v);                   // logits tiny: no max needed
    Ssum += we;
    acc = fmaf(we, xl, acc);
  }
  XR_HG[rowbase + lane] = acc / Ssum + gbl[lane];
}

// ---------------------------------------------------------------------------
// Fully fused GRU step: gi = hg@WihT+bih, gh = hp@WhhT+bhh, gates, h out.
// Thread = (row, 16-col group). Both W slabs in LDS [6][64][pad20].
// ---------------------------------------------------------------------------
template <int HASP>
__global__ __launch_bounds__(256) void k_gru_step(
    const float* __restrict__ hg, const float* __restrict__ hp,
    const float* __restrict__ Wih, const float* __restrict__ Whh,
    const float* __restrict__ bih, const float* __restrict__ bhh,
    float* __restrict__ hout) {
  __shared__ float wlds[6 * 64 * 20];   // [g][k][jj], pad 16->20
  int tid = threadIdx.x;
  int j0 = blockIdx.y * 16;
  for (int idx = tid; idx < 6 * 64 * 16; idx += 256) {
    int g = idx >> 10;
    int jj = (idx >> 6) & 15;
    int k = idx & 63;
    const float* src = (g < 3) ? (Wih + ((size_t)((g << 6) + j0 + jj) << 6))
                               : (Whh + ((size_t)(((g - 3) << 6) + j0 + jj) << 6));
    wlds[((g << 6) + k) * 20 + jj] = src[k];
  }
  __syncthreads();
  int r = blockIdx.x * 256 + tid;

  float4 acc[6][4];
#pragma unroll
  for (int g = 0; g < 6; ++g) {
    const float* bb = ((g < 3) ? (bih + (g << 6)) : (bhh + ((g - 3) << 6))) + j0;
#pragma unroll
    for (int q = 0; q < 4; ++q) acc[g][q] = *(const float4*)(bb + 4 * q);
  }

  const float* hgr = hg + ((size_t)r << 6);
  const float* hpr = HASP ? (hp + ((size_t)r << 6)) : nullptr;
  for (int kc = 0; kc < 64; kc += 4) {
    float4 xg = *(const float4*)(hgr + kc);
    float xga[4] = {xg.x, xg.y, xg.z, xg.w};
    float xpa[4];
    if (HASP) {
      float4 xp4 = *(const float4*)(hpr + kc);
      xpa[0] = xp4.x; xpa[1] = xp4.y; xpa[2] = xp4.z; xpa[3] = xp4.w;
    }
#pragma unroll
    for (int q = 0; q < 4; ++q) {
      int k = kc + q;
      const float* wb = wlds + k * 20;
#pragma unroll
      for (int g = 0; g < 6; ++g) {
        if (!HASP && g >= 3) continue;
        float s = (g < 3) ? xga[q] : xpa[q];
        const float4* wp = (const float4*)(wb + g * 1280);
#pragma unroll
        for (int q4 = 0; q4 < 4; ++q4) {
          float4 w = wp[q4];
          acc[g][q4].x = fmaf(w.x, s, acc[g][q4].x);
          acc[g][q4].y = fmaf(w.y, s, acc[g][q4].y);
          acc[g][q4].z = fmaf(w.z, s, acc[g][q4].z);
          acc[g][q4].w = fmaf(w.w, s, acc[g][q4].w);
        }
      }
    }
  }

  size_t ob = ((size_t)r << 6) + j0;
#pragma unroll
  for (int q = 0; q < 4; ++q) {
    float4 hv = make_float4(0.f, 0.f, 0.f, 0.f);
    if (HASP) hv = *(const float4*)(hpr + j0 + 4 * q);
    float4 o;
    {
      float rg = sigf(acc[0][q].x + acc[3][q].x);
      float zg = sigf(acc[1][q].x + acc[4][q].x);
      float ng = tanhfast(acc[2][q].x + rg * acc[5][q].x);
      o.x = (1.f - zg) * ng + zg * hv.x;
    }
    {
      float rg = sigf(acc[0][q].y + acc[3][q].y);
      float zg = sigf(acc[1][q].y + acc[4][q].y);
      float ng = tanhfast(acc[2][q].y + rg * acc[5][q].y);
      o.y = (1.f - zg) * ng + zg * hv.y;
    }
    {
      float rg = sigf(acc[0][q].z + acc[3][q].z);
      float zg = sigf(acc[1][q].z + acc[4][q].z);
      float ng = tanhfast(acc[2][q].z + rg * acc[5][q].z);
      o.z = (1.f - zg) * ng + zg * hv.z;
    }
    {
      float rg = sigf(acc[0][q].w + acc[3][q].w);
      float zg = sigf(acc[1][q].w + acc[4][q].w);
      float ng = tanhfast(acc[2][q].w + rg * acc[5][q].w);
      o.w = (1.f - zg) * ng + zg * hv.w;
    }
    *(float4*)(hout + ob + 4 * q) = o;
  }
}

// ---------------------------------------------------------------------------
// Output heads
// ---------------------------------------------------------------------------
__global__ __launch_bounds__(256) void k_heads(
    const float* __restrict__ Xb,
    const float* __restrict__ oW1, const float* __restrict__ ob1,
    const float* __restrict__ oW2, const float* __restrict__ ob2,
    const float* __restrict__ dW1, const float* __restrict__ db1,
    const float* __restrict__ dW2, const float* __restrict__ db2,
    float* __restrict__ out) {
  __shared__ float w1o[Hh * HB2], w1d[Hh * HB2];
  __shared__ float w2o[HB2], w2d[HB2], b1o[HB2], b1d[HB2];
  int tid = threadIdx.x;
  for (int idx = tid; idx < Hh * HB2; idx += 256) { w1o[idx] = oW1[idx]; w1d[idx] = dW1[idx]; }
  if (tid < HB2) { w2o[tid] = oW2[tid]; w2d[tid] = dW2[tid]; b1o[tid] = ob1[tid]; b1d[tid] = db1[tid]; }
  __syncthreads();
  int r = blockIdx.x * 256 + tid;
  if (r >= Bb * Nn) return;
  int b = r >> 11, n = r & (Nn - 1);
  const float* xrow = Xb + (((size_t)b * Ss + (Ss - 1)) * Nn + n) * Hh;
  float x[Hh];
  const float4* xp = (const float4*)xrow;
#pragma unroll
  for (int q = 0; q < Hh / 4; ++q) {
    float4 v = xp[q];
    x[4 * q] = v.x; x[4 * q + 1] = v.y; x[4 * q + 2] = v.z; x[4 * q + 3] = v.w;
  }
  float acco = ob2[0], accd = db2[0];
  for (int j = 0; j < HB2; ++j) {
    float ho = b1o[j], hd = b1d[j];
#pragma unroll
    for (int k = 0; k < Hh; ++k) {
      ho += x[k] * w1o[k * HB2 + j];
      hd += x[k] * w1d[k * HB2 + j];
    }
    acco += fmaxf(ho, 0.f) * w2o[j];
    accd += fmaxf(hd, 0.f) * w2d[j];
  }
  out[r] = acco;
  out[Bb * Nn + r] = accd;
}

// ---------------------------------------------------------------------------
extern "C" void kernel_launch(void* const* d_in, const int* in_sizes, int n_in,
                              void* d_out, int out_size, void* d_ws, size_t ws_size,
                              hipStream_t stream) {
  const float* x   = (const float*)d_in[0];
  const int*   ei  = (const int*)d_in[1];
  const float* ea  = (const float*)d_in[2];
  const float* Wp  = (const float*)d_in[3];
  const float* bp  = (const float*)d_in[4];
  const float* Wl  = (const float*)d_in[5];
  const float* bl  = (const float*)d_in[6];
  const float* Wr  = (const float*)d_in[7];
  const float* br  = (const float*)d_in[8];
  const float* We  = (const float*)d_in[9];
  const float* att = (const float*)d_in[10];
  const float* gb  = (const float*)d_in[11];
  const float* Wih = (const float*)d_in[12];
  const float* Whh = (const float*)d_in[13];
  const float* bih = (const float*)d_in[14];
  const float* bhh = (const float*)d_in[15];
  const float* oW1 = (const float*)d_in[16];
  const float* ob1 = (const float*)d_in[17];
  const float* oW2 = (const float*)d_in[18];
  const float* ob2 = (const float*)d_in[19];
  const float* dW1 = (const float*)d_in[20];
  const float* db1 = (const float*)d_in[21];
  const float* dW2 = (const float*)d_in[22];
  const float* db2 = (const float*)d_in[23];
  float* out = (float*)d_out;

  // workspace layout (floats)
  float* f    = (float*)d_ws;
  float* Xb   = f;                          // 131072*64
  float* XLb  = Xb  + (size_t)RTOT * Hh;    // 131072*64
  float* XRb  = XLb + (size_t)RTOT * Hh;    // 131072*64 (hg after k_gat)
  float* EPb  = XRb + (size_t)RTOT * Hh;    // 18432*64
  float* cntF = EPb + (size_t)E2c * Hh;     // 2048
  float* loopA = cntF + Nn;                 // 2048*8
  int*   fillI = (int*)(loopA + Nn * EFf);  // 2048
  int*   offs  = fillI + Nn;                // 2049 (+pad)
  int*   eidA  = offs + 2052;               // 18432
  int*   srcA  = eidA + E2c;                // 18432

  hipMemsetAsync(cntF, 0, (size_t)(Nn + Nn * EFf + Nn) * 4, stream);

  k_loop_accum<<<dim3((Ee * EFf + 255) / 256), 256, 0, stream>>>(ei, ea, cntF, loopA);
  k_loop_div<<<dim3((Nn * EFf + 255) / 256), 256, 0, stream>>>(loopA, cntF);
  k_scan<<<1, 256, 0, stream>>>(cntF, offs);
  k_scatter<<<dim3((E2c + 255) / 256), 256, 0, stream>>>(ei, offs, fillI, eidA, srcA);

  // X = x @ Wp + bp
  k_gemm<Ff><<<dim3(RTOT / 256, 1), 256, 0, stream>>>(x, Wp, bp, Xb, RTOT, Hh, 0);

  for (int l = 0; l < 2; ++l) {
    k_ep<<<dim3((E2c * Hh + 255) / 256), 256, 0, stream>>>(
        ea, loopA, We + (size_t)l * EFf * Hh, EPb);
    k_xlr<<<dim3(RTOT / 256, 4), 256, 0, stream>>>(
        Xb, Wl + (size_t)l * Hh * Hh, bl + (size_t)l * Hh,
        Wr + (size_t)l * Hh * Hh, br + (size_t)l * Hh, XLb, XRb);
    k_gat<<<dim3(RTOT * Hh / 256), 256, 0, stream>>>(
        XLb, XRb, EPb, offs, eidA, srcA, att + (size_t)l * Hh, gb + (size_t)l * Hh);
    const float* Wih_l = Wih + (size_t)l * 192 * Hh;
    const float* Whh_l = Whh + (size_t)l * 192 * Hh;
    const float* bih_l = bih + (size_t)l * 192;
    const float* bhh_l = bhh + (size_t)l * 192;
    for (int t = 0; t < Bb; ++t) {
      const float* hg_t = XRb + (size_t)t * Mm * Hh;
      float* h_out = Xb + (size_t)t * Mm * Hh;
      if (t == 0) {
        k_gru_step<0><<<dim3(Mm / 256, 4), 256, 0, stream>>>(
            hg_t, nullptr, Wih_l, Whh_l, bih_l, bhh_l, h_out);
      } else {
        const float* h_prev = Xb + (size_t)(t - 1) * Mm * Hh;
        k_gru_step<1><<<dim3(Mm / 256, 4), 256, 0, stream>>>(
            hg_t, h_prev, Wih_l, Whh_l, bih_l, bhh_l, h_out);
      }
    }
  }

  k_heads<<<dim3((Bb * Nn + 255) / 256), 256, 0, stream>>>(
      Xb, oW1, ob1, oW2, ob2, dW1, db1, dW2, db2, out);
}

// Round 3
// 744.496 us; speedup vs baseline: 1.4418x; 1.1147x over previous
//
#include <hip/hip_runtime.h>
#include <math.h>

#define Bb   4
#define Ss   16
#define Nn   2048
#define Ff   32
#define Ee   16384
#define EFf  8
#define Hh   64
#define HB2  32
#define E2c  (Ee + Nn)          // 18432
#define RTOT (Bb*Ss*Nn)         // 131072
#define Mm   (Ss*Nn)            // 32768

__device__ __forceinline__ float sigf(float x) { return 1.f / (1.f + __expf(-x)); }
__device__ __forceinline__ float tanhfast(float x) { return 2.f / (1.f + __expf(-2.f * x)) - 1.f; }

// ---------------------------------------------------------------------------
// Self-loop attr accumulation
// ---------------------------------------------------------------------------
__global__ __launch_bounds__(256) void k_loop_accum(
    const int* __restrict__ ei, const float* __restrict__ ea,
    float* __restrict__ cntF, float* __restrict__ loopA) {
  int idx = blockIdx.x * 256 + threadIdx.x;
  int e = idx >> 3, j = idx & 7;
  int d = ei[Ee + e];
  atomicAdd(&loopA[d * EFf + j], ea[idx]);
  if (j == 0) atomicAdd(&cntF[d], 1.0f);
}

__global__ __launch_bounds__(256) void k_loop_div(
    float* __restrict__ loopA, const float* __restrict__ cntF) {
  int idx = blockIdx.x * 256 + threadIdx.x;
  loopA[idx] /= fmaxf(cntF[idx >> 3], 1.0f);
}

// ---------------------------------------------------------------------------
// Exclusive scan of per-dst counts (+1 self loop) -> offs[0..2048]
// ---------------------------------------------------------------------------
__global__ __launch_bounds__(256) void k_scan(
    const float* __restrict__ cntF, int* __restrict__ offs) {
  __shared__ int partial[256];
  int tid = threadIdx.x;
  int base = tid * 8;
  int vals[8];
  int s = 0;
  for (int i = 0; i < 8; ++i) {
    int c = (int)cntF[base + i] + 1;
    vals[i] = c;
    s += c;
  }
  partial[tid] = s;
  __syncthreads();
  for (int off = 1; off < 256; off <<= 1) {
    int v = partial[tid];
    int add = (tid >= off) ? partial[tid - off] : 0;
    __syncthreads();
    partial[tid] = v + add;
    __syncthreads();
  }
  int run = (tid == 0) ? 0 : partial[tid - 1];
  for (int i = 0; i < 8; ++i) {
    offs[base + i] = run;
    run += vals[i];
  }
  if (tid == 255) offs[Nn] = run;
}

// ---------------------------------------------------------------------------
// Scatter edges into CSR-by-dst; also record posOf[e] so EP can be written
// directly in CSR order (turns k_gat's EP gather into a contiguous stream).
// ---------------------------------------------------------------------------
__global__ __launch_bounds__(256) void k_scatter(
    const int* __restrict__ ei, const int* __restrict__ offs,
    int* __restrict__ fillI, int* __restrict__ posOf, int* __restrict__ srcA) {
  int e = blockIdx.x * 256 + threadIdx.x;
  if (e >= E2c) return;
  int d = (e < Ee) ? ei[Ee + e] : (e - Ee);
  int s = (e < Ee) ? ei[e]      : (e - Ee);
  int pos = offs[d] + atomicAdd(&fillI[d], 1);
  posOf[e] = pos;
  srcA[pos] = s;
}

// ---------------------------------------------------------------------------
// Transpose Wih/Whh to k-major: WT[l][k][j<192: ih, 192..383: hh]
// ---------------------------------------------------------------------------
__global__ __launch_bounds__(256) void k_wtr(
    const float* __restrict__ Wih, const float* __restrict__ Whh,
    float* __restrict__ WT) {
  int idx = blockIdx.x * 256 + threadIdx.x;   // 2*64*384 = 49152
  int l = idx / (64 * 384);
  int k = (idx / 384) & 63;
  int j = idx % 384;
  float v = (j < 192) ? Wih[((size_t)l * 192 + j) * 64 + k]
                      : Whh[((size_t)l * 192 + (j - 192)) * 64 + k];
  WT[idx] = v;
}

// ---------------------------------------------------------------------------
// ep = ea_f @ We[l], written in CSR order (EPc[posOf[e]])
// ---------------------------------------------------------------------------
__global__ __launch_bounds__(256) void k_ep(
    const float* __restrict__ ea, const float* __restrict__ loopA,
    const float* __restrict__ We, const int* __restrict__ posOf,
    float* __restrict__ EPc) {
  __shared__ float wlds[EFf * Hh];
  int tid = threadIdx.x;
  if (tid < EFf * Hh) wlds[tid] = We[tid];
  if (tid + 256 < EFf * Hh) wlds[tid + 256] = We[tid + 256];
  __syncthreads();
  int idx = blockIdx.x * 256 + tid;
  int e = idx >> 6, j = idx & 63;
  const float* a = (e < Ee) ? (ea + (size_t)e * EFf) : (loopA + (size_t)(e - Ee) * EFf);
  float acc = 0.f;
#pragma unroll
  for (int k = 0; k < EFf; ++k) acc += a[k] * wlds[k * Hh + j];
  EPc[(((size_t)posOf[e]) << 6) + j] = acc;
}

// ---------------------------------------------------------------------------
// proj: Out[r][0..63] = bp + x[r][0..31] @ Wp. lane=row, W via uniform s_load.
// ---------------------------------------------------------------------------
__global__ __launch_bounds__(256) void k_proj(
    const float* __restrict__ X, const float* __restrict__ Wp,
    const float* __restrict__ bp, float* __restrict__ Out) {
  int r = blockIdx.x * 256 + threadIdx.x;
  float acc[64];
#pragma unroll
  for (int j = 0; j < 64; ++j) acc[j] = bp[j];
  const float4* xp = (const float4*)(X + (size_t)r * 32);
#pragma unroll 1
  for (int kc = 0; kc < 8; ++kc) {
    float4 xv = xp[kc];
    float xa[4] = {xv.x, xv.y, xv.z, xv.w};
#pragma unroll
    for (int q = 0; q < 4; ++q) {
      const float* w = Wp + ((4 * kc + q) << 6);
#pragma unroll
      for (int j = 0; j < 64; ++j) acc[j] = fmaf(xa[q], w[j], acc[j]);
    }
  }
  float4* op = (float4*)(Out + ((size_t)r << 6));
#pragma unroll
  for (int q = 0; q < 16; ++q)
    op[q] = make_float4(acc[4*q], acc[4*q+1], acc[4*q+2], acc[4*q+3]);
}

// ---------------------------------------------------------------------------
// Fused XL/XR: lane=row, full 64-col accumulators for both mats, W via s_load.
// ---------------------------------------------------------------------------
__global__ __launch_bounds__(256) void k_xlr(
    const float* __restrict__ X,
    const float* __restrict__ Wl_, const float* __restrict__ bl_,
    const float* __restrict__ Wr_, const float* __restrict__ br_,
    float* __restrict__ XL, float* __restrict__ XR) {
  int r = blockIdx.x * 256 + threadIdx.x;
  float accL[64], accR[64];
#pragma unroll
  for (int j = 0; j < 64; ++j) { accL[j] = bl_[j]; accR[j] = br_[j]; }
  const float4* xp = (const float4*)(X + ((size_t)r << 6));
#pragma unroll 1
  for (int kc = 0; kc < 16; ++kc) {
    float4 xv = xp[kc];
    float xa[4] = {xv.x, xv.y, xv.z, xv.w};
#pragma unroll
    for (int q = 0; q < 4; ++q) {
      int k = 4 * kc + q;
      const float* wL = Wl_ + (k << 6);
      const float* wR = Wr_ + (k << 6);
#pragma unroll
      for (int j = 0; j < 64; ++j) {
        accL[j] = fmaf(xa[q], wL[j], accL[j]);
        accR[j] = fmaf(xa[q], wR[j], accR[j]);
      }
    }
  }
  float4* oL = (float4*)(XL + ((size_t)r << 6));
  float4* oR = (float4*)(XR + ((size_t)r << 6));
#pragma unroll
  for (int q = 0; q < 16; ++q) {
    oL[q] = make_float4(accL[4*q], accL[4*q+1], accL[4*q+2], accL[4*q+3]);
    oR[q] = make_float4(accR[4*q], accR[4*q+1], accR[4*q+2], accR[4*q+3]);
  }
}

// ---------------------------------------------------------------------------
// GATv2: wave per (g,d), lane = h. 4-wide edge pipelining, CSR-ordered EP.
// ---------------------------------------------------------------------------
__global__ __launch_bounds__(256) void k_gat(
    const float* __restrict__ XL, float* __restrict__ XR_HG,
    const float* __restrict__ EPc, const int* __restrict__ offs,
    const int* __restrict__ srcA,
    const float* __restrict__ att, const float* __restrict__ gbl) {
  int gw = (blockIdx.x * 256 + threadIdx.x) >> 6;
  int lane = threadIdx.x & 63;
  int g = gw >> 11;
  int d = gw & (Nn - 1);
  float attv = att[lane];
  float gbv = gbl[lane];
  size_t rowbase = ((size_t)gw) << 6;
  float xr = XR_HG[rowbase + lane];
  int p0 = offs[d], p1 = offs[d + 1];
  int nE = p1 - p0;
  int srcv = 0;
  if (lane < nE) srcv = srcA[p0 + lane];
  const float* XLg = XL + (((size_t)g * Nn) << 6);
  const float* EPp = EPc + (((size_t)p0) << 6) + lane;
  float Ssum = 0.f, acc = 0.f;
  int nE4 = nE < 64 ? nE : 64;
  int p = 0;
  for (; p + 4 <= nE4; p += 4) {
    int s0 = __shfl(srcv, p,     64);
    int s1 = __shfl(srcv, p + 1, 64);
    int s2 = __shfl(srcv, p + 2, 64);
    int s3 = __shfl(srcv, p + 3, 64);
    float xl0 = XLg[(s0 << 6) + lane];
    float xl1 = XLg[(s1 << 6) + lane];
    float xl2 = XLg[(s2 << 6) + lane];
    float xl3 = XLg[(s3 << 6) + lane];
    float ep0 = EPp[(p + 0) << 6];
    float ep1 = EPp[(p + 1) << 6];
    float ep2 = EPp[(p + 2) << 6];
    float ep3 = EPp[(p + 3) << 6];
    float m0 = xl0 + xr + ep0; m0 = fmaxf(m0, 0.2f * m0);
    float m1 = xl1 + xr + ep1; m1 = fmaxf(m1, 0.2f * m1);
    float m2 = xl2 + xr + ep2; m2 = fmaxf(m2, 0.2f * m2);
    float m3 = xl3 + xr + ep3; m3 = fmaxf(m3, 0.2f * m3);
    float v0 = m0 * attv, v1 = m1 * attv, v2 = m2 * attv, v3 = m3 * attv;
#pragma unroll
    for (int w = 1; w < 64; w <<= 1) {
      v0 += __shfl_xor(v0, w, 64);
      v1 += __shfl_xor(v1, w, 64);
      v2 += __shfl_xor(v2, w, 64);
      v3 += __shfl_xor(v3, w, 64);
    }
    float w0 = __expf(v0), w1 = __expf(v1), w2 = __expf(v2), w3 = __expf(v3);
    Ssum += (w0 + w1) + (w2 + w3);
    acc = fmaf(w0, xl0, acc);
    acc = fmaf(w1, xl1, acc);
    acc = fmaf(w2, xl2, acc);
    acc = fmaf(w3, xl3, acc);
  }
  for (; p < nE; ++p) {
    int s = (p < 64) ? __shfl(srcv, p, 64) : srcA[p0 + p];
    float xl = XLg[(s << 6) + lane];
    float ep = EPp[p << 6];
    float m = xl + xr + ep; m = fmaxf(m, 0.2f * m);
    float v = m * attv;
#pragma unroll
    for (int w = 1; w < 64; w <<= 1) v += __shfl_xor(v, w, 64);
    float we = __expf(v);
    Ssum += we;
    acc = fmaf(we, xl, acc);
  }
  XR_HG[rowbase + lane] = acc / Ssum + gbv;
}

// ---------------------------------------------------------------------------
// Fused GRU step: lane=row, 8-col slice per blockIdx.y, W (k-major) via s_load.
// ---------------------------------------------------------------------------
template <int HASP>
__global__ __launch_bounds__(256) void k_gru_step(
    const float* __restrict__ hg, const float* __restrict__ hp,
    const float* __restrict__ WTl,
    const float* __restrict__ bih, const float* __restrict__ bhh,
    float* __restrict__ hout) {
  int r = blockIdx.x * 256 + threadIdx.x;
  int j0 = blockIdx.y * 8;
  float acc[6][8];
#pragma unroll
  for (int g = 0; g < 3; ++g)
#pragma unroll
    for (int j = 0; j < 8; ++j) acc[g][j] = bih[(g << 6) + j0 + j];
  if (HASP) {
#pragma unroll
    for (int g = 0; g < 3; ++g)
#pragma unroll
      for (int j = 0; j < 8; ++j) acc[3 + g][j] = bhh[(g << 6) + j0 + j];
  }
  const float4* hgp = (const float4*)(hg + ((size_t)r << 6));
  const float4* hpp = (const float4*)((HASP ? hp : hg) + ((size_t)r << 6));
#pragma unroll 2
  for (int kc = 0; kc < 16; ++kc) {
    float4 xg4 = hgp[kc];
    float xg[4] = {xg4.x, xg4.y, xg4.z, xg4.w};
    float xp[4];
    if (HASP) {
      float4 t = hpp[kc];
      xp[0] = t.x; xp[1] = t.y; xp[2] = t.z; xp[3] = t.w;
    }
#pragma unroll
    for (int q = 0; q < 4; ++q) {
      const float* wrow = WTl + (4 * kc + q) * 384 + j0;
#pragma unroll
      for (int g = 0; g < 3; ++g)
#pragma unroll
        for (int j = 0; j < 8; ++j)
          acc[g][j] = fmaf(xg[q], wrow[(g << 6) + j], acc[g][j]);
      if (HASP) {
#pragma unroll
        for (int g = 0; g < 3; ++g)
#pragma unroll
          for (int j = 0; j < 8; ++j)
            acc[3 + g][j] = fmaf(xp[q], wrow[192 + (g << 6) + j], acc[3 + g][j]);
      }
    }
  }
  float hv[8] = {0, 0, 0, 0, 0, 0, 0, 0};
  if (HASP) {
    const float* hpr = hp + ((size_t)r << 6) + j0;
#pragma unroll
    for (int j = 0; j < 8; ++j) hv[j] = hpr[j];
  }
  float o[8];
#pragma unroll
  for (int j = 0; j < 8; ++j) {
    float ghr = HASP ? acc[3][j] : bhh[j0 + j];
    float ghz = HASP ? acc[4][j] : bhh[64 + j0 + j];
    float ghn = HASP ? acc[5][j] : bhh[128 + j0 + j];
    float rg = sigf(acc[0][j] + ghr);
    float zg = sigf(acc[1][j] + ghz);
    float ng = tanhfast(acc[2][j] + rg * ghn);
    o[j] = (1.f - zg) * ng + zg * hv[j];
  }
  float* op = hout + ((size_t)r << 6) + j0;
  *(float4*)(op)     = make_float4(o[0], o[1], o[2], o[3]);
  *(float4*)(op + 4) = make_float4(o[4], o[5], o[6], o[7]);
}

// ---------------------------------------------------------------------------
// Output heads
// ---------------------------------------------------------------------------
__global__ __launch_bounds__(256) void k_heads(
    const float* __restrict__ Xb,
    const float* __restrict__ oW1, const float* __restrict__ ob1,
    const float* __restrict__ oW2, const float* __restrict__ ob2,
    const float* __restrict__ dW1, const float* __restrict__ db1,
    const float* __restrict__ dW2, const float* __restrict__ db2,
    float* __restrict__ out) {
  __shared__ float w1o[Hh * HB2], w1d[Hh * HB2];
  __shared__ float w2o[HB2], w2d[HB2], b1o[HB2], b1d[HB2];
  int tid = threadIdx.x;
  for (int idx = tid; idx < Hh * HB2; idx += 256) { w1o[idx] = oW1[idx]; w1d[idx] = dW1[idx]; }
  if (tid < HB2) { w2o[tid] = oW2[tid]; w2d[tid] = dW2[tid]; b1o[tid] = ob1[tid]; b1d[tid] = db1[tid]; }
  __syncthreads();
  int r = blockIdx.x * 256 + tid;
  int b = r >> 11, n = r & (Nn - 1);
  const float* xrow = Xb + (((size_t)b * Ss + (Ss - 1)) * Nn + n) * Hh;
  float x[Hh];
  const float4* xp = (const float4*)xrow;
#pragma unroll
  for (int q = 0; q < Hh / 4; ++q) {
    float4 v = xp[q];
    x[4*q] = v.x; x[4*q+1] = v.y; x[4*q+2] = v.z; x[4*q+3] = v.w;
  }
  float acco = ob2[0], accd = db2[0];
  for (int j = 0; j < HB2; ++j) {
    float ho = b1o[j], hd = b1d[j];
#pragma unroll
    for (int k = 0; k < Hh; ++k) {
      ho += x[k] * w1o[k * HB2 + j];
      hd += x[k] * w1d[k * HB2 + j];
    }
    acco += fmaxf(ho, 0.f) * w2o[j];
    accd += fmaxf(hd, 0.f) * w2d[j];
  }
  out[r] = acco;
  out[Bb * Nn + r] = accd;
}

// ---------------------------------------------------------------------------
extern "C" void kernel_launch(void* const* d_in, const int* in_sizes, int n_in,
                              void* d_out, int out_size, void* d_ws, size_t ws_size,
                              hipStream_t stream) {
  const float* x   = (const float*)d_in[0];
  const int*   ei  = (const int*)d_in[1];
  const float* ea  = (const float*)d_in[2];
  const float* Wp  = (const float*)d_in[3];
  const float* bp  = (const float*)d_in[4];
  const float* Wl  = (const float*)d_in[5];
  const float* bl  = (const float*)d_in[6];
  const float* Wr  = (const float*)d_in[7];
  const float* br  = (const float*)d_in[8];
  const float* We  = (const float*)d_in[9];
  const float* att = (const float*)d_in[10];
  const float* gb  = (const float*)d_in[11];
  const float* Wih = (const float*)d_in[12];
  const float* Whh = (const float*)d_in[13];
  const float* bih = (const float*)d_in[14];
  const float* bhh = (const float*)d_in[15];
  const float* oW1 = (const float*)d_in[16];
  const float* ob1 = (const float*)d_in[17];
  const float* oW2 = (const float*)d_in[18];
  const float* ob2 = (const float*)d_in[19];
  const float* dW1 = (const float*)d_in[20];
  const float* db1 = (const float*)d_in[21];
  const float* dW2 = (const float*)d_in[22];
  const float* db2 = (const float*)d_in[23];
  float* out = (float*)d_out;

  // workspace layout (floats)
  float* f    = (float*)d_ws;
  float* Xb   = f;                          // 131072*64
  float* XLb  = Xb  + (size_t)RTOT * Hh;    // 131072*64
  float* XRb  = XLb + (size_t)RTOT * Hh;    // 131072*64 (hg after k_gat)
  float* EPc  = XRb + (size_t)RTOT * Hh;    // 18432*64 (CSR order)
  float* WTb  = EPc + (size_t)E2c * Hh;     // 2*64*384
  float* cntF = WTb + 2 * 64 * 384;         // 2048
  float* loopA = cntF + Nn;                 // 2048*8
  int*   fillI = (int*)(loopA + Nn * EFf);  // 2048
  int*   offs  = fillI + Nn;                // 2049 (+pad)
  int*   posOf = offs + 2052;               // 18432
  int*   srcA  = posOf + E2c;               // 18432

  // zero cnt / loop_attr / fill (contiguous)
  hipMemsetAsync(cntF, 0, (size_t)(Nn + Nn * EFf + Nn) * 4, stream);

  k_loop_accum<<<dim3(Ee * EFf / 256), 256, 0, stream>>>(ei, ea, cntF, loopA);
  k_loop_div<<<dim3(Nn * EFf / 256), 256, 0, stream>>>(loopA, cntF);
  k_scan<<<1, 256, 0, stream>>>(cntF, offs);
  k_scatter<<<dim3((E2c + 255) / 256), 256, 0, stream>>>(ei, offs, fillI, posOf, srcA);
  k_wtr<<<dim3(2 * 64 * 384 / 256), 256, 0, stream>>>(Wih, Whh, WTb);

  // X = x @ Wp + bp
  k_proj<<<dim3(RTOT / 256), 256, 0, stream>>>(x, Wp, bp, Xb);

  for (int l = 0; l < 2; ++l) {
    k_ep<<<dim3(E2c * Hh / 256), 256, 0, stream>>>(
        ea, loopA, We + (size_t)l * EFf * Hh, posOf, EPc);
    k_xlr<<<dim3(RTOT / 256), 256, 0, stream>>>(
        Xb, Wl + (size_t)l * Hh * Hh, bl + (size_t)l * Hh,
        Wr + (size_t)l * Hh * Hh, br + (size_t)l * Hh, XLb, XRb);
    k_gat<<<dim3(RTOT * Hh / 256), 256, 0, stream>>>(
        XLb, XRb, EPc, offs, srcA, att + (size_t)l * Hh, gb + (size_t)l * Hh);
    const float* WTl = WTb + (size_t)l * 64 * 384;
    const float* bih_l = bih + (size_t)l * 192;
    const float* bhh_l = bhh + (size_t)l * 192;
    for (int t = 0; t < Bb; ++t) {
      const float* hg_t = XRb + (size_t)t * Mm * Hh;
      float* h_out = Xb + (size_t)t * Mm * Hh;
      if (t == 0) {
        k_gru_step<0><<<dim3(Mm / 256, 8), 256, 0, stream>>>(
            hg_t, nullptr, WTl, bih_l, bhh_l, h_out);
      } else {
        const float* h_prev = Xb + (size_t)(t - 1) * Mm * Hh;
        k_gru_step<1><<<dim3(Mm / 256, 8), 256, 0, stream>>>(
            hg_t, h_prev, WTl, bih_l, bhh_l, h_out);
      }
    }
  }

  k_heads<<<dim3(Bb * Nn / 256), 256, 0, stream>>>(
      Xb, oW1, ob1, oW2, ob2, dW1, db1, dW2, db2, out);
}